// Round 3
// baseline (454.282 us; speedup 1.0000x reference)
//
#include <hip/hip_runtime.h>

// Cross product along dim=1 of (16, 3, 1024, 1024) fp32 tensors.
// Layout (row-major): idx = ((b*3 + c)*1024 + h)*1024 + w.
// Component stride = P = 1024*1024 floats; batch stride = 3*P.
// Memory-bound: 604 MB kernel traffic; streaming ceiling ~6.3 TB/s -> ~96 us floor.
//
// R3: same as R2 but with clang ext_vector_type(4) instead of HIP float4 —
// __builtin_nontemporal_store requires a native vector type, not the
// HIP_vector_type struct. 2x float4 per thread (12 outstanding loads) +
// nontemporal stores (output never re-read; don't evict inputs from LLC).

typedef float f4 __attribute__((ext_vector_type(4)));

#define P4 (1024 * 1024 / 4)   // f4 per component plane (262144, pow2)

__global__ __launch_bounds__(256) void cross_kernel(
    const f4* __restrict__ a,
    const f4* __restrict__ b,
    f4* __restrict__ out)
{
    // Each block handles 512 consecutive f4 positions (2 per thread,
    // stride-256 for coalescing). 512 | P4, so a block never crosses a
    // plane or batch boundary -> single batch/base computation, no bounds check.
    int i0 = blockIdx.x * 512 + threadIdx.x;

    int batch = i0 >> 18;          // i0 / P4
    int r     = i0 & (P4 - 1);     // i0 % P4
    long base = (long)batch * (3 * P4) + r;

    // Issue all 12 loads before any dependent use: max outstanding vmcnt.
    f4 a0l = a[base];
    f4 a1l = a[base + P4];
    f4 a2l = a[base + 2 * P4];
    f4 b0l = b[base];
    f4 b1l = b[base + P4];
    f4 b2l = b[base + 2 * P4];
    f4 a0h = a[base + 256];
    f4 a1h = a[base + P4 + 256];
    f4 a2h = a[base + 2 * P4 + 256];
    f4 b0h = b[base + 256];
    f4 b1h = b[base + P4 + 256];
    f4 b2h = b[base + 2 * P4 + 256];

    // ext_vector_type supports elementwise arithmetic directly.
    f4 c0l = a1l * b2l - a2l * b1l;
    f4 c1l = a2l * b0l - a0l * b2l;
    f4 c2l = a0l * b1l - a1l * b0l;
    f4 c0h = a1h * b2h - a2h * b1h;
    f4 c1h = a2h * b0h - a0h * b2h;
    f4 c2h = a0h * b1h - a1h * b0h;

    __builtin_nontemporal_store(c0l, &out[base]);
    __builtin_nontemporal_store(c1l, &out[base + P4]);
    __builtin_nontemporal_store(c2l, &out[base + 2 * P4]);
    __builtin_nontemporal_store(c0h, &out[base + 256]);
    __builtin_nontemporal_store(c1h, &out[base + P4 + 256]);
    __builtin_nontemporal_store(c2h, &out[base + 2 * P4 + 256]);
}

extern "C" void kernel_launch(void* const* d_in, const int* in_sizes, int n_in,
                              void* d_out, int out_size, void* d_ws, size_t ws_size,
                              hipStream_t stream) {
    const f4* a = (const f4*)d_in[0];
    const f4* b = (const f4*)d_in[1];
    f4* out = (f4*)d_out;

    // out_size = 16*3*1024*1024 floats; f4 positions = out_size/12 = 4,194,304
    int n4 = out_size / 12;
    int block = 256;
    int grid = n4 / (block * 2);   // 8192 blocks, 2 f4 per thread
    cross_kernel<<<grid, block, 0, stream>>>(a, b, out);
}